// Round 2
// 259.134 us; speedup vs baseline: 1.0023x; 1.0023x over previous
//
#include <hip/hip_runtime.h>

// Problem constants (fixed by setup_inputs: B=64, Z=256, F=128, T=2048, C=5)
#define BATCH   64
#define FDIM    128
#define TDIM    2048
#define CDIM    5
#define ZN      (64 * 256)     // mean / log_var element count
#define MSEBLK  1024           // mse partial blocks: 64 b * 16 t-tiles
#define NPART   (MSEBLK + 2)   // + ce slot + kld slot

// Kernel 1: 1026 blocks.
//   blk 0 -> cross-entropy partial (overlaps the HBM-bound MSE phase: free VALU)
//   blk 1 -> KLD partial            (ditto; its 128 kB load overlaps too)
//   blk 2..1025 -> per-block partial of sum_{b,t} ( sum_f (o - tg) )^2
// CE/KLD blocks are FIRST so they dispatch earliest and fully overlap.
// FP op order is kept bit-identical to the round-0 2-kernel version
// (virtual-thread staging + identical 1024-wide reduction trees).
__global__ __launch_bounds__(256) void main_partials(const float* __restrict__ o,
                                                     const float* __restrict__ tg,
                                                     const float* __restrict__ mean,
                                                     const float* __restrict__ log_var,
                                                     const float* __restrict__ oclas,
                                                     const int* __restrict__ tclas,
                                                     float* __restrict__ partial) {
    const int blk = blockIdx.x;
    const int tid = threadIdx.x;

    if (blk >= 2) {
        // ---- MSE partial (identical math/order to previous mse_partials) ----
        const int mblk = blk - 2;           // 0..1023
        const int b    = mblk >> 4;         // / 16
        const int tile = mblk & 15;         // 16 tiles of 128 t
        const int fg   = tid >> 5;          // 0..7  (f-group of 16 rows)
        const int tq   = tid & 31;          // 0..31 (float4 column slot)

        const size_t base = (size_t)b * (2 * FDIM * TDIM) + (size_t)(fg * 16) * TDIM
                          + tile * 128 + tq * 4;
        const float* po = o  + base;
        const float* pt = tg + base;

        float4 s = make_float4(0.f, 0.f, 0.f, 0.f);
#pragma unroll
        for (int i = 0; i < 16; ++i) {
            float4 a = *(const float4*)(po + (size_t)i * TDIM);
            float4 c = *(const float4*)(pt + (size_t)i * TDIM);
            s.x += a.x - c.x;
            s.y += a.y - c.y;
            s.z += a.z - c.z;
            s.w += a.w - c.w;
        }

        __shared__ float4 red[256];
        __shared__ float  red2[32];
        red[tid] = s;
        __syncthreads();

        if (tid < 32) {
            float4 c = red[tid];
#pragma unroll
            for (int g = 1; g < 8; ++g) {
                float4 r = red[g * 32 + tid];
                c.x += r.x; c.y += r.y; c.z += r.z; c.w += r.w;
            }
            // square per t-column (each component is one column's full f-sum)
            red2[tid] = c.x * c.x + c.y * c.y + c.z * c.z + c.w * c.w;
        }
        __syncthreads();

        if (tid == 0) {
            float acc = 0.f;
#pragma unroll
            for (int i = 0; i < 32; ++i) acc += red2[i];
            partial[mblk] = acc;
        }
        return;
    }

    // ---- CE (blk==0) / KLD (blk==1) ----
    // Stage 1024 virtual-thread values into LDS, then reduce with the exact
    // same 1024-wide tree the old tail_kernel used (bit-identical result).
    __shared__ float tree[1024];

    if (blk == 0) {
        // Cross-entropy: virtual thread v<64 owns row v; v>=64 contributes 0.
        for (int v = tid; v < 1024; v += 256) {
            float cl = 0.0f;
            if (v < BATCH) {
                const float* row = oclas + v * CDIM;
                float mx = row[0];
#pragma unroll
                for (int c = 1; c < CDIM; ++c) mx = fmaxf(mx, row[c]);
                float se = 0.0f;
#pragma unroll
                for (int c = 0; c < CDIM; ++c) se += expf(row[c] - mx);
                int tc = tclas[v];
                cl = -(row[tc] - mx - logf(se));
            }
            tree[v] = cl;
        }
    } else {
        // KLD: virtual thread v owns idx = v + i*1024, i = 0..15 (same as before)
        for (int v = tid; v < 1024; v += 256) {
            float kld = 0.0f;
#pragma unroll
            for (int i = 0; i < ZN / 1024; ++i) {
                int idx = v + i * 1024;
                float m  = mean[idx];
                float lv = log_var[idx];
                kld += -0.5f * (1.0f + lv - m * m - expf(lv));
            }
            tree[v] = kld;
        }
    }
    __syncthreads();

    // 1024-wide tree emulated by 256 threads: same adds, same slots, same order.
    for (int off = 512; off > 0; off >>= 1) {
        for (int j = tid; j < off; j += 256) {
            tree[j] += tree[j + off];
        }
        __syncthreads();
    }
    if (tid == 0) partial[MSEBLK + blk] = tree[0];
}

// Kernel 2 (single 256-thread block): reduce 1024 mse partials (same tree as
// the old 1024-thread tail) + combine with staged CE/KLD scalars.
__global__ __launch_bounds__(256) void tail_reduce(const float* __restrict__ partial,
                                                   const float* __restrict__ w,
                                                   float* __restrict__ out) {
    const int tid = threadIdx.x;
    __shared__ float tree[1024];

    // 256 threads x float4 = 1024 staged values (pure copy, no arithmetic)
    float4 v = ((const float4*)partial)[tid];
    tree[tid * 4 + 0] = v.x;
    tree[tid * 4 + 1] = v.y;
    tree[tid * 4 + 2] = v.z;
    tree[tid * 4 + 3] = v.w;
    __syncthreads();

    for (int off = 512; off > 0; off >>= 1) {
        for (int j = tid; j < off; j += 256) {
            tree[j] += tree[j + off];
        }
        __syncthreads();
    }

    if (tid == 0) {
        float mse       = 4.0f * tree[0];              // ISSQ scale 2 on each signal
        float kld       = partial[MSEBLK + 1];
        float clas_loss = partial[MSEBLK] / (float)BATCH;
        out[0] = w[0] * mse + w[1] * kld + w[2] * clas_loss;
    }
}

extern "C" void kernel_launch(void* const* d_in, const int* in_sizes, int n_in,
                              void* d_out, int out_size, void* d_ws, size_t ws_size,
                              hipStream_t stream) {
    const float* mean    = (const float*)d_in[0];
    const float* log_var = (const float*)d_in[1];
    const float* orec    = (const float*)d_in[2];
    const float* oclas   = (const float*)d_in[3];
    const float* trec    = (const float*)d_in[4];
    const int*   tclas   = (const int*)d_in[5];
    // d_in[6] = batch_size, d_in[7] = img_size (constants hardcoded)
    const float* w       = (const float*)d_in[8];
    float* out           = (float*)d_out;
    float* partial       = (float*)d_ws;   // NPART floats, all slots overwritten

    main_partials<<<NPART, 256, 0, stream>>>(orec, trec, mean, log_var, oclas, tclas, partial);
    tail_reduce<<<1, 256, 0, stream>>>(partial, w, out);
}